// Round 1
// baseline (100.387 us; speedup 1.0000x reference)
//
#include <hip/hip_runtime.h>

#define OC 32
#define IC 16
#define HH 128
#define WW 128
#define NB 8

// Prep: cw[m*OC+i] = cos(theta[i*j, k]); sw[m*OC+i] = -sin(theta[i*j, k]); m = j*3+k
__global__ void prep_kernel(const float* __restrict__ theta,
                            float* __restrict__ cw, float* __restrict__ sw) {
    int t = blockIdx.x * blockDim.x + threadIdx.x;
    if (t >= OC * IC * 3) return;
    int i = t / (IC * 3);
    int rem = t - i * (IC * 3);
    int j = rem / 3;
    int k = rem - j * 3;
    float v = theta[(i * j) * 3 + k];
    int m = j * 3 + k;
    cw[m * OC + i] = __cosf(v);
    sw[m * OC + i] = -__sinf(v);
}

__global__ __launch_bounds__(256) void qconv_kernel(
        const float* __restrict__ x,
        const float* __restrict__ cw,
        const float* __restrict__ sw,
        float* __restrict__ out) {
    int p = blockIdx.x * 256 + threadIdx.x;
    int w = p & (WW - 1);
    int h = (p >> 7) & (HH - 1);
    int n = p >> 14;

    float2 acc[OC / 2];
#pragma unroll
    for (int ii = 0; ii < OC / 2; ++ii) acc[ii] = make_float2(0.f, 0.f);

    const float* xn = x + (size_t)n * IC * HH * WW;

    for (int j = 0; j < IC; ++j) {
        const float* xj = xn + j * HH * WW;
#pragma unroll
        for (int k = 0; k < 3; ++k) {
            int r = h + k - 1;
            float s = 0.f;
            if (r >= 0 && r < HH) {
                const float* row = xj + r * WW;
                float c0 = row[w];
                float cm = (w > 0)      ? row[w - 1] : 0.f;
                float cp = (w < WW - 1) ? row[w + 1] : 0.f;
                s = cm + c0 + cp;
            }
            float sn, cs;
            __sincosf(s, &sn, &cs);
            int m = j * 3 + k;
            const float2* cw2 = (const float2*)(cw + m * OC);
            const float2* sw2 = (const float2*)(sw + m * OC);
#pragma unroll
            for (int ii = 0; ii < OC / 2; ++ii) {
                float2 cc = cw2[ii];
                float2 ss = sw2[ii];
                acc[ii].x = fmaf(cs, cc.x, fmaf(sn, ss.x, acc[ii].x));
                acc[ii].y = fmaf(cs, cc.y, fmaf(sn, ss.y, acc[ii].y));
            }
        }
    }

    const float inv3 = 1.0f / 3.0f;
    float* outp = out + (size_t)n * OC * HH * WW + h * WW + w;
#pragma unroll
    for (int ii = 0; ii < OC / 2; ++ii) {
        outp[(size_t)(2 * ii) * HH * WW]     = acc[ii].x * inv3;
        outp[(size_t)(2 * ii + 1) * HH * WW] = acc[ii].y * inv3;
    }
}

extern "C" void kernel_launch(void* const* d_in, const int* in_sizes, int n_in,
                              void* d_out, int out_size, void* d_ws, size_t ws_size,
                              hipStream_t stream) {
    const float* x     = (const float*)d_in[0];
    const float* theta = (const float*)d_in[1];
    float* out = (float*)d_out;
    float* cw = (float*)d_ws;
    float* sw = cw + OC * IC * 3;

    prep_kernel<<<(OC * IC * 3 + 255) / 256, 256, 0, stream>>>(theta, cw, sw);

    int total = NB * HH * WW;
    qconv_kernel<<<total / 256, 256, 0, stream>>>(x, cw, sw, out);
}

// Round 2
// 96.869 us; speedup vs baseline: 1.0363x; 1.0363x over previous
//
#include <hip/hip_runtime.h>

#define OC 32
#define IC 16
#define HH 128
#define WW 128
#define NB 8
#define NG 4              // channel groups (threadIdx.y)
#define CPG (OC / NG)     // 8 channels per group
#define NM (IC * 3)       // 48 (j,k) pairs

// One kernel: block computes trig weights into LDS, then each thread
// accumulates 8 output channels for one pixel.
// Block: threadIdx.x in [0,64) -> w within chunk (one wave per channel group),
//        threadIdx.y in [0,4)  -> channel group.
// Grid:  blockIdx.x = n*256 + h*2 + wchunk   (2048 blocks)
__global__ __launch_bounds__(256, 4) void qconv_kernel(
        const float* __restrict__ x,
        const float* __restrict__ theta,
        float* __restrict__ out) {
    __shared__ float cw_s[NM * OC];
    __shared__ float sw_s[NM * OC];

    int t = threadIdx.y * 64 + threadIdx.x;
    // Fill weights: q = m*32 + i, m = j*3+k
#pragma unroll
    for (int q = t; q < NM * OC; q += 256) {
        int m = q >> 5;
        int i = q & 31;
        int j = m / 3;
        int k = m - j * 3;
        float v = theta[(i * j) * 3 + k];
        float sn, cs;
        __sincosf(v, &sn, &cs);
        cw_s[q] = cs;
        sw_s[q] = -sn;
    }
    __syncthreads();

    int bid = blockIdx.x;
    int wbase = (bid & 1) * 64;
    int h = (bid >> 1) & (HH - 1);
    int n = bid >> 8;
    int w = wbase + threadIdx.x;
    int g = threadIdx.y;

    float acc[CPG];
#pragma unroll
    for (int c = 0; c < CPG; ++c) acc[c] = 0.f;

    const float* xn = x + (size_t)n * IC * HH * WW;
    const float* cwg = cw_s + g * CPG;
    const float* swg = sw_s + g * CPG;

#pragma unroll 2
    for (int j = 0; j < IC; ++j) {
        const float* xj = xn + j * HH * WW;
#pragma unroll
        for (int k = 0; k < 3; ++k) {
            int r = h + k - 1;
            float s = 0.f;
            if (r >= 0 && r < HH) {
                const float* row = xj + r * WW;
                float c0 = row[w];
                float cm = (w > 0)      ? row[w - 1] : 0.f;
                float cp = (w < WW - 1) ? row[w + 1] : 0.f;
                s = cm + c0 + cp;
            }
            float sn, cs;
            __sincosf(s, &sn, &cs);
            int m = j * 3 + k;
            const float4* c4 = (const float4*)(cwg + m * OC);
            const float4* s4 = (const float4*)(swg + m * OC);
#pragma unroll
            for (int q = 0; q < 2; ++q) {
                float4 cc = c4[q];
                float4 ss = s4[q];
                acc[4 * q + 0] = fmaf(cs, cc.x, fmaf(sn, ss.x, acc[4 * q + 0]));
                acc[4 * q + 1] = fmaf(cs, cc.y, fmaf(sn, ss.y, acc[4 * q + 1]));
                acc[4 * q + 2] = fmaf(cs, cc.z, fmaf(sn, ss.z, acc[4 * q + 2]));
                acc[4 * q + 3] = fmaf(cs, cc.w, fmaf(sn, ss.w, acc[4 * q + 3]));
            }
        }
    }

    const float inv3 = 1.0f / 3.0f;
    float* outp = out + (size_t)n * OC * HH * WW + (size_t)(g * CPG) * HH * WW
                  + h * WW + w;
#pragma unroll
    for (int c = 0; c < CPG; ++c) {
        outp[(size_t)c * HH * WW] = acc[c] * inv3;
    }
}

extern "C" void kernel_launch(void* const* d_in, const int* in_sizes, int n_in,
                              void* d_out, int out_size, void* d_ws, size_t ws_size,
                              hipStream_t stream) {
    const float* x     = (const float*)d_in[0];
    const float* theta = (const float*)d_in[1];
    float* out = (float*)d_out;

    dim3 block(64, NG, 1);
    int nblocks = NB * HH * 2;   // 2048
    qconv_kernel<<<nblocks, block, 0, stream>>>(x, theta, out);
}